// Round 6
// baseline (192.137 us; speedup 1.0000x reference)
//
#include <hip/hip_runtime.h>
#include <hip/hip_bf16.h>

#define SEQ 2048
#define BATCH 4
#define EMBED 768
#define NHEAD 12
#define HDIM 64
#define NROWS (SEQ*BATCH)        // 8192
#define GH (BATCH*NHEAD)         // 48
#define KVBLK 64

typedef __bf16 bf16;
typedef __attribute__((ext_vector_type(4))) __bf16 bf16x4;
typedef __attribute__((ext_vector_type(8))) __bf16 bf16x8;
typedef __attribute__((ext_vector_type(4))) float f32x4;

#define LOG2E 1.44269504088896340736f

// ---------------- fp32 -> bf16 convert (x) ----------------
__global__ __launch_bounds__(256) void cvt_kernel(const float* __restrict__ in,
                                                  bf16* __restrict__ out, int n4) {
  int i = blockIdx.x * 256 + threadIdx.x;
  if (i >= n4) return;
  float4 v = reinterpret_cast<const float4*>(in)[i];
  bf16x4 o;
  o[0] = (bf16)v.x; o[1] = (bf16)v.y; o[2] = (bf16)v.z; o[3] = (bf16)v.w;
  reinterpret_cast<bf16x4*>(out)[i] = o;
}

// ---------------- 4 weight converts in one launch; q,k,v go into concat buffer ----
__global__ __launch_bounds__(256) void cvt_w4(const float* __restrict__ Wq,
                                              const float* __restrict__ Wk,
                                              const float* __restrict__ Wv,
                                              const float* __restrict__ Wo,
                                              bf16* __restrict__ Wqkvb,
                                              bf16* __restrict__ Wob) {
  const int n4 = EMBED * EMBED / 4;  // 147456
  int i = blockIdx.x * 256 + threadIdx.x;
  if (i >= n4) return;
  const float* src;
  bf16* dst;
  switch (blockIdx.y) {
    case 0: src = Wq; dst = Wqkvb; break;
    case 1: src = Wk; dst = Wqkvb + EMBED * EMBED; break;
    case 2: src = Wv; dst = Wqkvb + 2 * EMBED * EMBED; break;
    default: src = Wo; dst = Wob; break;
  }
  float4 v = reinterpret_cast<const float4*>(src)[i];
  bf16x4 o;
  o[0] = (bf16)v.x; o[1] = (bf16)v.y; o[2] = (bf16)v.z; o[3] = (bf16)v.w;
  reinterpret_cast<bf16x4*>(dst)[i] = o;
}

// ---------------- fused QKV GEMM: C[M,2304] = A[8192,768] @ Wqkv[2304,768]^T -------
// blockIdx.y 0-5 -> Q (*0.125*log2e, head layout), 6-11 -> K, 12-17 -> V^T
__global__ __launch_bounds__(256) void gemm_qkv(const bf16* __restrict__ A,
                                                const bf16* __restrict__ B,
                                                const float* __restrict__ bq,
                                                const float* __restrict__ bk,
                                                const float* __restrict__ bv,
                                                bf16* __restrict__ Qh,
                                                bf16* __restrict__ Kh,
                                                bf16* __restrict__ Vt) {
  constexpr int K = EMBED;
  __shared__ bf16 As[128 * 32];
  __shared__ bf16 Bs[128 * 32];
  const int tid = threadIdx.x;
  const int l = tid & 63;
  const int w = tid >> 6;
  const int row0 = blockIdx.x * 128;
  const int col0 = blockIdx.y * 128;
  const int wm = (w >> 1) * 64;
  const int wn = (w & 1) * 64;
  const int l15 = l & 15, l4 = l >> 4;

  f32x4 acc[4][4] = {};

  for (int k0 = 0; k0 < K; k0 += 32) {
#pragma unroll
    for (int i = 0; i < 2; ++i) {
      int c = tid + i * 256;
      int r = c >> 2, cc = c & 3;
      __builtin_amdgcn_global_load_lds(
          (const __attribute__((address_space(1))) void*)(A + (size_t)(row0 + r) * K + k0 + cc * 8),
          (__attribute__((address_space(3))) void*)(As + c * 8), 16, 0, 0);
    }
#pragma unroll
    for (int i = 0; i < 2; ++i) {
      int c = tid + i * 256;
      int r = c >> 2, cc = c & 3;
      __builtin_amdgcn_global_load_lds(
          (const __attribute__((address_space(1))) void*)(B + (size_t)(col0 + r) * K + k0 + cc * 8),
          (__attribute__((address_space(3))) void*)(Bs + c * 8), 16, 0, 0);
    }
    __syncthreads();

    bf16x8 af[4], bfr[4];
#pragma unroll
    for (int i = 0; i < 4; ++i)
      af[i] = *reinterpret_cast<const bf16x8*>(&As[(wm + i * 16 + l15) * 32 + l4 * 8]);
#pragma unroll
    for (int j = 0; j < 4; ++j)
      bfr[j] = *reinterpret_cast<const bf16x8*>(&Bs[(wn + j * 16 + l15) * 32 + l4 * 8]);
#pragma unroll
    for (int i = 0; i < 4; ++i)
#pragma unroll
      for (int j = 0; j < 4; ++j)
        acc[i][j] = __builtin_amdgcn_mfma_f32_16x16x32_bf16(af[i], bfr[j], acc[i][j], 0, 0, 0);
    __syncthreads();
  }

  const int sel = blockIdx.y / 6;                       // 0=Q 1=K 2=V (block-uniform)
  const float* bias = sel == 0 ? bq : (sel == 1 ? bk : bv);
  const int colbase = col0 - sel * EMBED;
#pragma unroll
  for (int i = 0; i < 4; ++i) {
#pragma unroll
    for (int j = 0; j < 4; ++j) {
      int col = colbase + wn + j * 16 + l15;
      float bia = bias[col];
#pragma unroll
      for (int r = 0; r < 4; ++r) {
        int row = row0 + wm + i * 16 + l4 * 4 + r;
        float v = acc[i][j][r] + bia;
        int t = row >> 2, bb = row & 3;      // row = t*BATCH + b
        int hh = col >> 6, d = col & 63;     // col = h*64 + d
        int g = bb * NHEAD + hh;             // fairseq head index b*H+h
        if (sel == 0)      Qh[((size_t)g * SEQ + t) * HDIM + d] = (bf16)(v * (0.125f * LOG2E));
        else if (sel == 1) Kh[((size_t)g * SEQ + t) * HDIM + d] = (bf16)v;
        else               Vt[((size_t)g * HDIM + d) * SEQ + t] = (bf16)v;  // transposed
      }
    }
  }
}

// ---------------- out-proj GEMM: out[8192,768] = attnb @ Wo^T + bo (fp32 out) ------
__global__ __launch_bounds__(256) void gemm_out(const bf16* __restrict__ A,
                                                const bf16* __restrict__ B,
                                                const float* __restrict__ bias,
                                                float* __restrict__ outp) {
  constexpr int K = EMBED;
  __shared__ bf16 As[128 * 32];
  __shared__ bf16 Bs[128 * 32];
  const int tid = threadIdx.x;
  const int l = tid & 63;
  const int w = tid >> 6;
  const int row0 = blockIdx.x * 128;
  const int col0 = blockIdx.y * 128;
  const int wm = (w >> 1) * 64;
  const int wn = (w & 1) * 64;
  const int l15 = l & 15, l4 = l >> 4;

  f32x4 acc[4][4] = {};

  for (int k0 = 0; k0 < K; k0 += 32) {
#pragma unroll
    for (int i = 0; i < 2; ++i) {
      int c = tid + i * 256;
      int r = c >> 2, cc = c & 3;
      __builtin_amdgcn_global_load_lds(
          (const __attribute__((address_space(1))) void*)(A + (size_t)(row0 + r) * K + k0 + cc * 8),
          (__attribute__((address_space(3))) void*)(As + c * 8), 16, 0, 0);
    }
#pragma unroll
    for (int i = 0; i < 2; ++i) {
      int c = tid + i * 256;
      int r = c >> 2, cc = c & 3;
      __builtin_amdgcn_global_load_lds(
          (const __attribute__((address_space(1))) void*)(B + (size_t)(col0 + r) * K + k0 + cc * 8),
          (__attribute__((address_space(3))) void*)(Bs + c * 8), 16, 0, 0);
    }
    __syncthreads();

    bf16x8 af[4], bfr[4];
#pragma unroll
    for (int i = 0; i < 4; ++i)
      af[i] = *reinterpret_cast<const bf16x8*>(&As[(wm + i * 16 + l15) * 32 + l4 * 8]);
#pragma unroll
    for (int j = 0; j < 4; ++j)
      bfr[j] = *reinterpret_cast<const bf16x8*>(&Bs[(wn + j * 16 + l15) * 32 + l4 * 8]);
#pragma unroll
    for (int i = 0; i < 4; ++i)
#pragma unroll
      for (int j = 0; j < 4; ++j)
        acc[i][j] = __builtin_amdgcn_mfma_f32_16x16x32_bf16(af[i], bfr[j], acc[i][j], 0, 0, 0);
    __syncthreads();
  }

#pragma unroll
  for (int i = 0; i < 4; ++i) {
#pragma unroll
    for (int j = 0; j < 4; ++j) {
      int col = col0 + wn + j * 16 + l15;
      float bia = bias[col];
#pragma unroll
      for (int r = 0; r < 4; ++r) {
        int row = row0 + wm + i * 16 + l4 * 4 + r;
        outp[(size_t)row * EMBED + col] = acc[i][j][r] + bia;
      }
    }
  }
}

// ---------------- Flash attention: q-tile 64, 5 blocks/CU, MFMA row-sums -----------
// Block = (head g, 64 q rows), 4 waves x 16 q. Head-affine XCD mapping (g=bid%48,
// bid%8 == g%8). LDS 28KB: K dbuf 16KB + V single 8KB + P 4KB -> 5 blocks/CU.
// V staged at step top, consumed after QK^T+exp (vmcnt(2) fence; V issued before K).
// P [16 q][32 kv] per wave, reused for both kv-halves (per-wave LDS is in-order).
// Row sums via MFMA with all-ones B operand -> no VALU adds, no end shuffles.
__global__ __launch_bounds__(256, 5) void attn_kernel(const bf16* __restrict__ Qh,
                                                      const bf16* __restrict__ Kh,
                                                      const bf16* __restrict__ Vt,
                                                      bf16* __restrict__ attnb) {
  const int g = blockIdx.x % GH;
  const int q0 = (blockIdx.x / GH) * 64;
  const int tid = threadIdx.x;
  const int w = tid >> 6, l = tid & 63;
  const int l15 = l & 15, l4 = l >> 4;
  const int qw = q0 + w * 16;

  __shared__ bf16 Ks[2][KVBLK * HDIM];   // 8KB x2: [kv][d], chunk-swizzled
  __shared__ bf16 Vs[HDIM * KVBLK];      // 8KB single: [d][kv], chunk-swizzled
  __shared__ bf16 P_all[4][16 * 32];     // 4KB: per-wave P half-tile, chunk-swizzled

  bf16* P = (bf16*)P_all[w];
  const bf16* Qp = Qh + (size_t)g * SEQ * HDIM;
  const bf16* Kp = Kh + (size_t)g * SEQ * HDIM;
  const bf16* Vp = Vt + (size_t)g * HDIM * SEQ;

#define STAGE_K(buf, kv0)                                                               \
  do {                                                                                  \
    _Pragma("unroll") for (int i = 0; i < 2; ++i) {                                     \
      int t = i * 256 + tid;                                                            \
      int r = t >> 3, c = t & 7;                                                        \
      __builtin_amdgcn_global_load_lds(                                                 \
          (const __attribute__((address_space(1))) void*)(Kp + (size_t)((kv0) + r) * HDIM + ((c ^ (r & 7)) * 8)), \
          (__attribute__((address_space(3))) void*)(&Ks[buf][t * 8]), 16, 0, 0);        \
    }                                                                                   \
  } while (0)

#define STAGE_V(kv0)                                                                    \
  do {                                                                                  \
    _Pragma("unroll") for (int i = 0; i < 2; ++i) {                                     \
      int t = i * 256 + tid;                                                            \
      int r = t >> 3, c = t & 7;                                                        \
      __builtin_amdgcn_global_load_lds(                                                 \
          (const __attribute__((address_space(1))) void*)(Vp + (size_t)r * SEQ + (kv0) + ((c ^ (r & 7)) * 8)), \
          (__attribute__((address_space(3))) void*)(&Vs[t * 8]), 16, 0, 0);             \
    }                                                                                   \
  } while (0)

  // Q fragments in regs: 2 k-steps (MFMA B-operand of swapped QK^T)
  bf16x8 aq[2];
#pragma unroll
  for (int ks = 0; ks < 2; ++ks)
    aq[ks] = *reinterpret_cast<const bf16x8*>(
        Qp + (size_t)(qw + l15) * HDIM + ks * 32 + l4 * 8);

  // all-ones B fragment for row-sum MFMA
  bf16x8 vone;
#pragma unroll
  for (int i = 0; i < 8; ++i) vone[i] = (bf16)1.0f;

  f32x4 acco[4] = {};     // O accumulator: rows q=l4*4+r, cols d=df*16+l15
  f32x4 accs = {};        // row-sum accumulator: rows q=l4*4+r (all cols equal)

  // hoisted P addresses (lane constants)
  const int ppr = l15 * 32;                          // P row base (elements)
  const int prd = ppr + ((l4 ^ (l15 & 3)) << 3);     // PV A-frag read addr

  STAGE_K(0, 0);
  __syncthreads();

  int cur = 0;
  for (int kv0 = 0; kv0 < SEQ; kv0 += KVBLK) {
    STAGE_V(kv0);                                   // V for THIS step (2 loads)
    STAGE_K(cur ^ 1, (kv0 + KVBLK) & (SEQ - 1));    // K for next step (2 loads, wraps)

    // ---- S^T = K Q^T from Ks[cur]; lane holds S[kv=kf*16+l4*4+r][q=qw+l15]
    f32x4 s[4] = {};
#pragma unroll
    for (int kf = 0; kf < 4; ++kf) {
      int row = kf * 16 + l15;
#pragma unroll
      for (int ks = 0; ks < 2; ++ks) {
        bf16x8 bk = *reinterpret_cast<const bf16x8*>(
            &Ks[cur][row * 64 + (((ks * 4 + l4) ^ (row & 7)) * 8)]);
        __builtin_amdgcn_s_setprio(1);
        s[kf] = __builtin_amdgcn_mfma_f32_16x16x32_bf16(bk, aq[ks], s[kf], 0, 0, 0);
        __builtin_amdgcn_s_setprio(0);
      }
    }

    // ---- half 0: exp2 for kf 0,1 -> P write; wait V; PV ks=0 (+ ones row-sum)
#pragma unroll
    for (int kf = 0; kf < 2; ++kf) {
      float p0 = exp2f(s[kf][0]), p1 = exp2f(s[kf][1]);
      float p2 = exp2f(s[kf][2]), p3 = exp2f(s[kf][3]);
      bf16x4 pk;
      pk[0] = (bf16)p0; pk[1] = (bf16)p1; pk[2] = (bf16)p2; pk[3] = (bf16)p3;
      int c = (kf & 1) * 2 + (l4 >> 1);
      *reinterpret_cast<bf16x4*>(&P[ppr + ((c ^ (l15 & 3)) << 3) + (l4 & 1) * 4]) = pk;
    }
    asm volatile("s_waitcnt vmcnt(2)" ::: "memory");   // V staged (K prefetch in flight)
    {
      bf16x8 ap = *reinterpret_cast<const bf16x8*>(&P[prd]);
#pragma unroll
      for (int df = 0; df < 4; ++df) {
        int row = df * 16 + l15;
        bf16x8 bv = *reinterpret_cast<const bf16x8*>(
            &Vs[row * 64 + ((l4 ^ (row & 7)) * 8)]);
        __builtin_amdgcn_s_setprio(1);
        acco[df] = __builtin_amdgcn_mfma_f32_16x16x32_bf16(ap, bv, acco[df], 0, 0, 0);
        __builtin_amdgcn_s_setprio(0);
      }
      __builtin_amdgcn_s_setprio(1);
      accs = __builtin_amdgcn_mfma_f32_16x16x32_bf16(ap, vone, accs, 0, 0, 0);
      __builtin_amdgcn_s_setprio(0);
    }

    // ---- half 1: exp2 for kf 2,3 -> P overwrite; PV ks=1 (+ ones row-sum)
#pragma unroll
    for (int kf = 2; kf < 4; ++kf) {
      float p0 = exp2f(s[kf][0]), p1 = exp2f(s[kf][1]);
      float p2 = exp2f(s[kf][2]), p3 = exp2f(s[kf][3]);
      bf16x4 pk;
      pk[0] = (bf16)p0; pk[1] = (bf16)p1; pk[2] = (bf16)p2; pk[3] = (bf16)p3;
      int c = (kf & 1) * 2 + (l4 >> 1);
      *reinterpret_cast<bf16x4*>(&P[ppr + ((c ^ (l15 & 3)) << 3) + (l4 & 1) * 4]) = pk;
    }
    {
      bf16x8 ap = *reinterpret_cast<const bf16x8*>(&P[prd]);
#pragma unroll
      for (int df = 0; df < 4; ++df) {
        int row = df * 16 + l15;
        bf16x8 bv = *reinterpret_cast<const bf16x8*>(
            &Vs[row * 64 + (((4 + l4) ^ (row & 7)) * 8)]);
        __builtin_amdgcn_s_setprio(1);
        acco[df] = __builtin_amdgcn_mfma_f32_16x16x32_bf16(ap, bv, acco[df], 0, 0, 0);
        __builtin_amdgcn_s_setprio(0);
      }
      __builtin_amdgcn_s_setprio(1);
      accs = __builtin_amdgcn_mfma_f32_16x16x32_bf16(ap, vone, accs, 0, 0, 0);
      __builtin_amdgcn_s_setprio(0);
    }

    __syncthreads();
    cur ^= 1;
  }

  // ---- normalize (accs rows already match acco rows) and store
  const int bb = g / NHEAD, hh = g % NHEAD;
#pragma unroll
  for (int r = 0; r < 4; ++r) {
    float rinv = __builtin_amdgcn_rcpf(accs[r]);
    int tq = qw + l4 * 4 + r;
#pragma unroll
    for (int df = 0; df < 4; ++df) {
      int d = df * 16 + l15;
      attnb[((size_t)tq * BATCH + bb) * EMBED + hh * HDIM + d] = (bf16)(acco[df][r] * rinv);
    }
  }
}

// ---------------- launch ----------------
extern "C" void kernel_launch(void* const* d_in, const int* in_sizes, int n_in,
                              void* d_out, int out_size, void* d_ws, size_t ws_size,
                              hipStream_t stream) {
  const float* x  = (const float*)d_in[0];
  const float* Wq = (const float*)d_in[1];
  const float* bq = (const float*)d_in[2];
  const float* Wk = (const float*)d_in[3];
  const float* bk = (const float*)d_in[4];
  const float* Wv = (const float*)d_in[5];
  const float* bv = (const float*)d_in[6];
  const float* Wo = (const float*)d_in[7];
  const float* bo = (const float*)d_in[8];
  float* out = (float*)d_out;

  char* ws = (char*)d_ws;
  bf16* xb    = (bf16*)(ws + 0);          // 8192*768*2   = 12582912
  bf16* Wqkvb = (bf16*)(ws + 12582912);   // 2304*768*2   = 3538944
  bf16* Wob   = (bf16*)(ws + 16121856);   // 768*768*2    = 1179648
  bf16* Qh    = (bf16*)(ws + 17301504);   // 48*2048*64*2 = 12582912
  bf16* Kh    = (bf16*)(ws + 29884416);
  bf16* Vt    = (bf16*)(ws + 42467328);
  bf16* attnb = (bf16*)(ws + 55050240);   // 8192*768*2

  cvt_kernel<<<6144, 256, 0, stream>>>(x, xb, NROWS * EMBED / 4);
  cvt_w4<<<dim3(576, 4), 256, 0, stream>>>(Wq, Wk, Wv, Wo, Wqkvb, Wob);

  gemm_qkv<<<dim3(NROWS / 128, 18), 256, 0, stream>>>(xb, Wqkvb, bq, bk, bv, Qh, Kh, Vt);

  attn_kernel<<<GH * (SEQ / 64), 256, 0, stream>>>(Qh, Kh, Vt, attnb);

  gemm_out<<<dim3(NROWS / 128, EMBED / 128), 256, 0, stream>>>(attnb, Wob, bo, out);
}

// Round 7
// 168.259 us; speedup vs baseline: 1.1419x; 1.1419x over previous
//
#include <hip/hip_runtime.h>
#include <hip/hip_bf16.h>

#define SEQ 2048
#define BATCH 4
#define EMBED 768
#define NHEAD 12
#define HDIM 64
#define NROWS (SEQ*BATCH)        // 8192
#define GH (BATCH*NHEAD)         // 48
#define KVBLK 64

typedef __bf16 bf16;
typedef __attribute__((ext_vector_type(4))) __bf16 bf16x4;
typedef __attribute__((ext_vector_type(8))) __bf16 bf16x8;
typedef __attribute__((ext_vector_type(4))) float f32x4;

#define LOG2E 1.44269504088896340736f

// ---------------- fp32 -> bf16 convert (x) ----------------
__global__ __launch_bounds__(256) void cvt_kernel(const float* __restrict__ in,
                                                  bf16* __restrict__ out, int n4) {
  int i = blockIdx.x * 256 + threadIdx.x;
  if (i >= n4) return;
  float4 v = reinterpret_cast<const float4*>(in)[i];
  bf16x4 o;
  o[0] = (bf16)v.x; o[1] = (bf16)v.y; o[2] = (bf16)v.z; o[3] = (bf16)v.w;
  reinterpret_cast<bf16x4*>(out)[i] = o;
}

// ---------------- 4 weight converts in one launch; q,k,v go into concat buffer ----
__global__ __launch_bounds__(256) void cvt_w4(const float* __restrict__ Wq,
                                              const float* __restrict__ Wk,
                                              const float* __restrict__ Wv,
                                              const float* __restrict__ Wo,
                                              bf16* __restrict__ Wqkvb,
                                              bf16* __restrict__ Wob) {
  const int n4 = EMBED * EMBED / 4;  // 147456
  int i = blockIdx.x * 256 + threadIdx.x;
  if (i >= n4) return;
  const float* src;
  bf16* dst;
  switch (blockIdx.y) {
    case 0: src = Wq; dst = Wqkvb; break;
    case 1: src = Wk; dst = Wqkvb + EMBED * EMBED; break;
    case 2: src = Wv; dst = Wqkvb + 2 * EMBED * EMBED; break;
    default: src = Wo; dst = Wob; break;
  }
  float4 v = reinterpret_cast<const float4*>(src)[i];
  bf16x4 o;
  o[0] = (bf16)v.x; o[1] = (bf16)v.y; o[2] = (bf16)v.z; o[3] = (bf16)v.w;
  reinterpret_cast<bf16x4*>(dst)[i] = o;
}

// ---------------- fused QKV GEMM: C[M,2304] = A[8192,768] @ Wqkv[2304,768]^T -------
// blockIdx.y 0-5 -> Q (*0.125*log2e, head layout), 6-11 -> K, 12-17 -> V^T
__global__ __launch_bounds__(256) void gemm_qkv(const bf16* __restrict__ A,
                                                const bf16* __restrict__ B,
                                                const float* __restrict__ bq,
                                                const float* __restrict__ bk,
                                                const float* __restrict__ bv,
                                                bf16* __restrict__ Qh,
                                                bf16* __restrict__ Kh,
                                                bf16* __restrict__ Vt) {
  constexpr int K = EMBED;
  __shared__ bf16 As[128 * 32];
  __shared__ bf16 Bs[128 * 32];
  const int tid = threadIdx.x;
  const int l = tid & 63;
  const int w = tid >> 6;
  const int row0 = blockIdx.x * 128;
  const int col0 = blockIdx.y * 128;
  const int wm = (w >> 1) * 64;
  const int wn = (w & 1) * 64;
  const int l15 = l & 15, l4 = l >> 4;

  f32x4 acc[4][4] = {};

  for (int k0 = 0; k0 < K; k0 += 32) {
#pragma unroll
    for (int i = 0; i < 2; ++i) {
      int c = tid + i * 256;
      int r = c >> 2, cc = c & 3;
      __builtin_amdgcn_global_load_lds(
          (const __attribute__((address_space(1))) void*)(A + (size_t)(row0 + r) * K + k0 + cc * 8),
          (__attribute__((address_space(3))) void*)(As + c * 8), 16, 0, 0);
    }
#pragma unroll
    for (int i = 0; i < 2; ++i) {
      int c = tid + i * 256;
      int r = c >> 2, cc = c & 3;
      __builtin_amdgcn_global_load_lds(
          (const __attribute__((address_space(1))) void*)(B + (size_t)(col0 + r) * K + k0 + cc * 8),
          (__attribute__((address_space(3))) void*)(Bs + c * 8), 16, 0, 0);
    }
    __syncthreads();

    bf16x8 af[4], bfr[4];
#pragma unroll
    for (int i = 0; i < 4; ++i)
      af[i] = *reinterpret_cast<const bf16x8*>(&As[(wm + i * 16 + l15) * 32 + l4 * 8]);
#pragma unroll
    for (int j = 0; j < 4; ++j)
      bfr[j] = *reinterpret_cast<const bf16x8*>(&Bs[(wn + j * 16 + l15) * 32 + l4 * 8]);
#pragma unroll
    for (int i = 0; i < 4; ++i)
#pragma unroll
      for (int j = 0; j < 4; ++j)
        acc[i][j] = __builtin_amdgcn_mfma_f32_16x16x32_bf16(af[i], bfr[j], acc[i][j], 0, 0, 0);
    __syncthreads();
  }

  const int sel = blockIdx.y / 6;                       // 0=Q 1=K 2=V (block-uniform)
  const float* bias = sel == 0 ? bq : (sel == 1 ? bk : bv);
  const int colbase = col0 - sel * EMBED;
#pragma unroll
  for (int i = 0; i < 4; ++i) {
#pragma unroll
    for (int j = 0; j < 4; ++j) {
      int col = colbase + wn + j * 16 + l15;
      float bia = bias[col];
#pragma unroll
      for (int r = 0; r < 4; ++r) {
        int row = row0 + wm + i * 16 + l4 * 4 + r;
        float v = acc[i][j][r] + bia;
        int t = row >> 2, bb = row & 3;      // row = t*BATCH + b
        int hh = col >> 6, d = col & 63;     // col = h*64 + d
        int g = bb * NHEAD + hh;             // fairseq head index b*H+h
        if (sel == 0)      Qh[((size_t)g * SEQ + t) * HDIM + d] = (bf16)(v * (0.125f * LOG2E));
        else if (sel == 1) Kh[((size_t)g * SEQ + t) * HDIM + d] = (bf16)v;
        else               Vt[((size_t)g * HDIM + d) * SEQ + t] = (bf16)v;  // transposed
      }
    }
  }
}

// ---------------- out-proj GEMM: out[8192,768] = attnb @ Wo^T + bo (fp32 out) ------
__global__ __launch_bounds__(256) void gemm_out(const bf16* __restrict__ A,
                                                const bf16* __restrict__ B,
                                                const float* __restrict__ bias,
                                                float* __restrict__ outp) {
  constexpr int K = EMBED;
  __shared__ bf16 As[128 * 32];
  __shared__ bf16 Bs[128 * 32];
  const int tid = threadIdx.x;
  const int l = tid & 63;
  const int w = tid >> 6;
  const int row0 = blockIdx.x * 128;
  const int col0 = blockIdx.y * 128;
  const int wm = (w >> 1) * 64;
  const int wn = (w & 1) * 64;
  const int l15 = l & 15, l4 = l >> 4;

  f32x4 acc[4][4] = {};

  for (int k0 = 0; k0 < K; k0 += 32) {
#pragma unroll
    for (int i = 0; i < 2; ++i) {
      int c = tid + i * 256;
      int r = c >> 2, cc = c & 3;
      __builtin_amdgcn_global_load_lds(
          (const __attribute__((address_space(1))) void*)(A + (size_t)(row0 + r) * K + k0 + cc * 8),
          (__attribute__((address_space(3))) void*)(As + c * 8), 16, 0, 0);
    }
#pragma unroll
    for (int i = 0; i < 2; ++i) {
      int c = tid + i * 256;
      int r = c >> 2, cc = c & 3;
      __builtin_amdgcn_global_load_lds(
          (const __attribute__((address_space(1))) void*)(B + (size_t)(col0 + r) * K + k0 + cc * 8),
          (__attribute__((address_space(3))) void*)(Bs + c * 8), 16, 0, 0);
    }
    __syncthreads();

    bf16x8 af[4], bfr[4];
#pragma unroll
    for (int i = 0; i < 4; ++i)
      af[i] = *reinterpret_cast<const bf16x8*>(&As[(wm + i * 16 + l15) * 32 + l4 * 8]);
#pragma unroll
    for (int j = 0; j < 4; ++j)
      bfr[j] = *reinterpret_cast<const bf16x8*>(&Bs[(wn + j * 16 + l15) * 32 + l4 * 8]);
#pragma unroll
    for (int i = 0; i < 4; ++i)
#pragma unroll
      for (int j = 0; j < 4; ++j)
        acc[i][j] = __builtin_amdgcn_mfma_f32_16x16x32_bf16(af[i], bfr[j], acc[i][j], 0, 0, 0);
    __syncthreads();
  }

#pragma unroll
  for (int i = 0; i < 4; ++i) {
#pragma unroll
    for (int j = 0; j < 4; ++j) {
      int col = col0 + wn + j * 16 + l15;
      float bia = bias[col];
#pragma unroll
      for (int r = 0; r < 4; ++r) {
        int row = row0 + wm + i * 16 + l4 * 4 + r;
        outp[(size_t)row * EMBED + col] = acc[i][j][r] + bia;
      }
    }
  }
}

// ---------------- Flash attention: r5 geometry + 40KB LDS (4 blocks/CU) ------------
// Block = (head g, 128 q rows), 4 waves x 32 q. Head-affine XCD mapping (g=bid%48).
// LDS 40KB exactly: K dbuf 16KB + V single 8KB + P 16KB -> 4 blocks/CU.
// V(t) staged at step top (issued BEFORE K(t+1) prefetch), first read mid-step
// after QK^T+exp (vmcnt(2) fence, "memory" clobber orders the Vs reads after it).
// Row sums via ones-operand MFMA -> no VALU adds, no end-of-kernel shuffles.
__global__ __launch_bounds__(256, 4) void attn_kernel(const bf16* __restrict__ Qh,
                                                      const bf16* __restrict__ Kh,
                                                      const bf16* __restrict__ Vt,
                                                      bf16* __restrict__ attnb) {
  const int g = blockIdx.x % GH;
  const int q0 = (blockIdx.x / GH) * 128;
  const int tid = threadIdx.x;
  const int w = tid >> 6, l = tid & 63;
  const int l15 = l & 15, l4 = l >> 4;
  const int qw = q0 + w * 32;

  __shared__ bf16 Ks[2][KVBLK * HDIM];   // 8KB x2: [kv][d], chunk-swizzled
  __shared__ bf16 Vs[HDIM * KVBLK];      // 8KB single: [d][kv], chunk-swizzled
  __shared__ bf16 P_all[4][32 * 64];     // 16KB: per-wave P tile, chunk-swizzled

  bf16* P = (bf16*)P_all[w];
  const bf16* Qp = Qh + (size_t)g * SEQ * HDIM;
  const bf16* Kp = Kh + (size_t)g * SEQ * HDIM;
  const bf16* Vp = Vt + (size_t)g * HDIM * SEQ;

#define STAGE_K(buf, kv0)                                                               \
  do {                                                                                  \
    _Pragma("unroll") for (int i = 0; i < 2; ++i) {                                     \
      int t = i * 256 + tid;                                                            \
      int r = t >> 3, c = t & 7;                                                        \
      __builtin_amdgcn_global_load_lds(                                                 \
          (const __attribute__((address_space(1))) void*)(Kp + (size_t)((kv0) + r) * HDIM + ((c ^ (r & 7)) * 8)), \
          (__attribute__((address_space(3))) void*)(&Ks[buf][t * 8]), 16, 0, 0);        \
    }                                                                                   \
  } while (0)

#define STAGE_V(kv0)                                                                    \
  do {                                                                                  \
    _Pragma("unroll") for (int i = 0; i < 2; ++i) {                                     \
      int t = i * 256 + tid;                                                            \
      int r = t >> 3, c = t & 7;                                                        \
      __builtin_amdgcn_global_load_lds(                                                 \
          (const __attribute__((address_space(1))) void*)(Vp + (size_t)r * SEQ + (kv0) + ((c ^ (r & 7)) * 8)), \
          (__attribute__((address_space(3))) void*)(&Vs[t * 8]), 16, 0, 0);             \
    }                                                                                   \
  } while (0)

  // Q fragments in regs: 2 q-frags x 2 k-steps (MFMA B-operand of swapped QK^T)
  bf16x8 aq[2][2];
#pragma unroll
  for (int qf = 0; qf < 2; ++qf)
#pragma unroll
    for (int ks = 0; ks < 2; ++ks)
      aq[qf][ks] = *reinterpret_cast<const bf16x8*>(
          Qp + (size_t)(qw + qf * 16 + l15) * HDIM + ks * 32 + l4 * 8);

  // all-ones B fragment for row-sum MFMA
  bf16x8 vone;
#pragma unroll
  for (int i = 0; i < 8; ++i) vone[i] = (bf16)1.0f;

  f32x4 acco[2][4] = {};   // O accumulator: rows q=qf*16+l4*4+r, cols d=df*16+l15
  f32x4 accs[2] = {};      // row-sum accumulator: same rows (all cols equal)

  STAGE_K(0, 0);
  __syncthreads();

  int cur = 0;
  for (int kv0 = 0; kv0 < SEQ; kv0 += KVBLK) {
    STAGE_V(kv0);                                   // V for THIS step (2 loads, first)
    STAGE_K(cur ^ 1, (kv0 + KVBLK) & (SEQ - 1));    // K for next step (2 loads, wraps)

    // ---- S^T = K Q^T from Ks[cur]; lane holds S[kv=kf*16+l4*4+r][q=qf*16+l15]
    f32x4 s[2][4] = {};
#pragma unroll
    for (int kf = 0; kf < 4; ++kf) {
      int row = kf * 16 + l15;
#pragma unroll
      for (int ks = 0; ks < 2; ++ks) {
        bf16x8 bk = *reinterpret_cast<const bf16x8*>(
            &Ks[cur][row * 64 + (((ks * 4 + l4) ^ (row & 7)) * 8)]);
        __builtin_amdgcn_s_setprio(1);
        s[0][kf] = __builtin_amdgcn_mfma_f32_16x16x32_bf16(bk, aq[0][ks], s[0][kf], 0, 0, 0);
        s[1][kf] = __builtin_amdgcn_mfma_f32_16x16x32_bf16(bk, aq[1][ks], s[1][kf], 0, 0, 0);
        __builtin_amdgcn_s_setprio(0);
      }
    }

    // ---- p = exp2(s); vectorized P store (one b64 per qf,kf)
#pragma unroll
    for (int qf = 0; qf < 2; ++qf) {
      int prow = qf * 16 + l15;
#pragma unroll
      for (int kf = 0; kf < 4; ++kf) {
        float p0 = exp2f(s[qf][kf][0]);
        float p1 = exp2f(s[qf][kf][1]);
        float p2 = exp2f(s[qf][kf][2]);
        float p3 = exp2f(s[qf][kf][3]);
        bf16x4 pk;
        pk[0] = (bf16)p0; pk[1] = (bf16)p1; pk[2] = (bf16)p2; pk[3] = (bf16)p3;
        // logical kv base = kf*16 + l4*4 -> chunk(16B) = 2*kf + (l4>>1), XOR row&7
        int chunk = (2 * kf + (l4 >> 1)) ^ (prow & 7);
        *reinterpret_cast<bf16x4*>(&P[prow * 64 + chunk * 8 + (l4 & 1) * 4]) = pk;
      }
    }

    // ---- V staged (K prefetch still in flight); also fences Vs reads below
    asm volatile("s_waitcnt vmcnt(2)" ::: "memory");

    // ---- O += P @ V from Vs; row sums via ones-MFMA (same A-frag)
#pragma unroll
    for (int ks = 0; ks < 2; ++ks) {
      bf16x8 ap[2];
#pragma unroll
      for (int qf = 0; qf < 2; ++qf) {
        int prow = qf * 16 + l15;
        int lc = ks * 4 + l4;
        ap[qf] = *reinterpret_cast<const bf16x8*>(P + prow * 64 + ((lc ^ (prow & 7)) << 3));
      }
#pragma unroll
      for (int df = 0; df < 4; ++df) {
        int row = df * 16 + l15;
        bf16x8 bv = *reinterpret_cast<const bf16x8*>(
            &Vs[row * 64 + (((ks * 4 + l4) ^ (row & 7)) * 8)]);
        __builtin_amdgcn_s_setprio(1);
        acco[0][df] = __builtin_amdgcn_mfma_f32_16x16x32_bf16(ap[0], bv, acco[0][df], 0, 0, 0);
        acco[1][df] = __builtin_amdgcn_mfma_f32_16x16x32_bf16(ap[1], bv, acco[1][df], 0, 0, 0);
        __builtin_amdgcn_s_setprio(0);
      }
      __builtin_amdgcn_s_setprio(1);
      accs[0] = __builtin_amdgcn_mfma_f32_16x16x32_bf16(ap[0], vone, accs[0], 0, 0, 0);
      accs[1] = __builtin_amdgcn_mfma_f32_16x16x32_bf16(ap[1], vone, accs[1], 0, 0, 0);
      __builtin_amdgcn_s_setprio(0);
    }
    __syncthreads();
    cur ^= 1;
  }

  // ---- normalize (accs rows already match acco rows) and store
  const int bb = g / NHEAD, hh = g % NHEAD;
#pragma unroll
  for (int qf = 0; qf < 2; ++qf)
#pragma unroll
    for (int r = 0; r < 4; ++r) {
      float rinv = __builtin_amdgcn_rcpf(accs[qf][r]);
      int tq = qw + qf * 16 + l4 * 4 + r;
#pragma unroll
      for (int df = 0; df < 4; ++df) {
        int d = df * 16 + l15;
        attnb[((size_t)tq * BATCH + bb) * EMBED + hh * HDIM + d] = (bf16)(acco[qf][df][r] * rinv);
      }
    }
}

// ---------------- launch ----------------
extern "C" void kernel_launch(void* const* d_in, const int* in_sizes, int n_in,
                              void* d_out, int out_size, void* d_ws, size_t ws_size,
                              hipStream_t stream) {
  const float* x  = (const float*)d_in[0];
  const float* Wq = (const float*)d_in[1];
  const float* bq = (const float*)d_in[2];
  const float* Wk = (const float*)d_in[3];
  const float* bk = (const float*)d_in[4];
  const float* Wv = (const float*)d_in[5];
  const float* bv = (const float*)d_in[6];
  const float* Wo = (const float*)d_in[7];
  const float* bo = (const float*)d_in[8];
  float* out = (float*)d_out;

  char* ws = (char*)d_ws;
  bf16* xb    = (bf16*)(ws + 0);          // 8192*768*2   = 12582912
  bf16* Wqkvb = (bf16*)(ws + 12582912);   // 2304*768*2   = 3538944
  bf16* Wob   = (bf16*)(ws + 16121856);   // 768*768*2    = 1179648
  bf16* Qh    = (bf16*)(ws + 17301504);   // 48*2048*64*2 = 12582912
  bf16* Kh    = (bf16*)(ws + 29884416);
  bf16* Vt    = (bf16*)(ws + 42467328);
  bf16* attnb = (bf16*)(ws + 55050240);   // 8192*768*2

  cvt_kernel<<<6144, 256, 0, stream>>>(x, xb, NROWS * EMBED / 4);
  cvt_w4<<<dim3(576, 4), 256, 0, stream>>>(Wq, Wk, Wv, Wo, Wqkvb, Wob);

  gemm_qkv<<<dim3(NROWS / 128, 18), 256, 0, stream>>>(xb, Wqkvb, bq, bk, bv, Qh, Kh, Vt);

  attn_kernel<<<GH * (SEQ / 128), 256, 0, stream>>>(Qh, Kh, Vt, attnb);

  gemm_out<<<dim3(NROWS / 128, EMBED / 128), 256, 0, stream>>>(attnb, Wob, bo, out);
}